// Round 5
// baseline (337.060 us; speedup 1.0000x reference)
//
#include <hip/hip_runtime.h>
#include <hip/hip_fp16.h>
#include <stdint.h>

#define Bn 32
#define Cc 64
#define Hh 112
#define Ww 112
#define HWp (Hh*Ww)            // 12544
#define NPIX (Bn*HWp)          // 401408
#define PW 114                 // padded width
#define PHW (PW*PW)            // 12996 padded cells per image
#define IW 110                 // interior width
#define IPX (IW*IW)            // 12100 interior pixels
#define NINT_BLK 48            // ceil(12100/256)
#define BPX 444                // border pixels per image
#define ALPHA 0.25f

// workspace layout (bytes)
#define WB1_OFF   0                      // uint64[64*9]
#define WB2_OFF   4608
#define ASC1_OFF  9216                   // float[64]  (= ALPHA * mean|w|)
#define ASC2_OFF  9472
#define CI1_OFF   9728                   // int[64*9]  cint[o*9+type]
#define CI2_OFF   12032
#define BITS1_OFF 16384                  // uint64[Bn*PHW] (padded, halo=0)
#define BITS2_OFF (16384 + 3326976)
#define OUT1H_OFF (16384 + 2*3326976)    // __half[NPIX*Cc] (fp16 path)
#define WS_NEED   (OUT1H_OFF + (size_t)NPIX*Cc*2)

// 128 blocks x 64 lanes; block b<64 -> conv1 tables (o=b), else conv2.
__global__ __launch_bounds__(64) void prep_weights(
        const float* __restrict__ w3, const float* __restrict__ wpw,
        uint64_t* __restrict__ wb1, uint64_t* __restrict__ wb2,
        float* __restrict__ asc1, float* __restrict__ asc2,
        int* __restrict__ ci1, int* __restrict__ ci2) {
    int b = blockIdx.x;
    int lane = threadIdx.x;
    const float* w  = (b < 64) ? w3   : wpw;
    uint64_t* wbits = (b < 64) ? wb1  : wb2;
    float*    ascp  = (b < 64) ? asc1 : asc2;
    int*      cip   = (b < 64) ? ci1  : ci2;
    int o = b & 63;
    const float* wp = w + ((size_t)o * Cc + lane) * 9;
    float v[9]; float asum = 0.f;
    #pragma unroll
    for (int t = 0; t < 9; ++t) { v[t] = wp[t]; asum += fabsf(v[t]); }
    uint64_t bal[9];
    #pragma unroll
    for (int t = 0; t < 9; ++t) bal[t] = __ballot(v[t] < 0.f);
    if (lane < 9) {
        wbits[o * 9 + lane] = bal[lane];
        int ty = lane, tr = ty / 3, tc = ty % 3;
        int sum = 0;
        #pragma unroll
        for (int t = 0; t < 9; ++t) {
            int r = t / 3, c = t % 3;
            bool inv = (tr == 0 && r == 0) || (tr == 2 && r == 2) ||
                       (tc == 0 && c == 0) || (tc == 2 && c == 2);
            if (inv) sum += 64 - 2 * (int)__popcll(bal[t]);
        }
        cip[o * 9 + ty] = 576 - sum;
    }
    #pragma unroll
    for (int off = 32; off > 0; off >>= 1) asum += __shfl_down(asum, off, 64);
    if (lane == 0) ascp[o] = ALPHA * asum * (1.f / 576.f);
}

// grid (51, Bn, 2): z-slice packs 32 channels into its 4B half of each 8B word.
// Halo cells: zero both bits1 and bits2 halves.
__global__ __launch_bounds__(256) void pack1(const float* __restrict__ x,
                                             const float* __restrict__ b11,
                                             uint32_t* __restrict__ bits1_32,
                                             uint32_t* __restrict__ bits2_32) {
    int pc = blockIdx.x * 256 + threadIdx.x;
    if (pc >= PHW) return;
    int n = blockIdx.y, z = blockIdx.z, cbase = z * 32;
    int ph = pc / PW, pw = pc - ph * PW;
    size_t wi = ((size_t)n * PHW + pc) * 2 + z;
    if (ph == 0 || ph == PW - 1 || pw == 0 || pw == PW - 1) {
        bits1_32[wi] = 0; bits2_32[wi] = 0;
        return;
    }
    int hw = (ph - 1) * Ww + (pw - 1);
    const float* xp = x + ((size_t)n * Cc + cbase) * HWp + hw;
    uint32_t m = 0;
    #pragma unroll 1
    for (int cc = 0; cc < 32; cc += 16) {
        float v[16];
        #pragma unroll
        for (int j = 0; j < 16; ++j) v[j] = xp[(size_t)(cc + j) * HWp];
        #pragma unroll
        for (int j = 0; j < 16; ++j)
            if (v[j] + b11[cbase + cc + j] < 0.f) m |= (1u << (cc + j));
    }
    bits1_32[wi] = m;
}

// p in [0,BPX) -> border (h,w)
__device__ __forceinline__ void border_map(int p, int& h, int& w) {
    if (p < 112)      { h = 0;   w = p; }
    else if (p < 224) { h = 111; w = p - 112; }
    else if (p < 334) { h = 1 + (p - 224); w = 0; }
    else              { h = 1 + (p - 334); w = 111; }
}

// conv1 + residual(x) + b12/prelu(a1)/b13 -> out1 (OutT); pack bits2 half-word.
// grid (50, Bn, 2): blocks 0..47 interior (no border logic), 48..49 border.
template <typename OutT>
__global__ __launch_bounds__(256) void conv1_ep(
        const float* __restrict__ x, const uint64_t* __restrict__ bits1,
        const uint64_t* __restrict__ wb, const float* __restrict__ asc,
        const int* __restrict__ cint,
        const float* __restrict__ b12, const float* __restrict__ a1,
        const float* __restrict__ b13, const float* __restrict__ b21,
        OutT* __restrict__ out1, uint32_t* __restrict__ bits2_32) {
    int n = blockIdx.y, z = blockIdx.z, obase = z * 32;
    int bx = blockIdx.x;
    bool interior = (bx < NINT_BLK);
    int h, w, t9 = 4;
    if (interior) {
        int p = bx * 256 + threadIdx.x;
        if (p >= IPX) return;
        int ph = p / IW;
        h = 1 + ph; w = 1 + (p - ph * IW);
    } else {
        int p = (bx - NINT_BLK) * 256 + threadIdx.x;
        if (p >= BPX) return;
        border_map(p, h, w);
        t9 = ((h == 0) ? 0 : (h == Hh - 1) ? 6 : 3) +
             ((w == 0) ? 0 : (w == Ww - 1) ? 2 : 1);
    }
    int hw = h * Ww + w;
    const uint64_t* bp = bits1 + (size_t)n * PHW + (h + 1) * PW + (w + 1);
    uint64_t w00 = bp[-PW - 1], w01 = bp[-PW], w02 = bp[-PW + 1];
    uint64_t w10 = bp[-1],      w11 = bp[0],   w12 = bp[1];
    uint64_t w20 = bp[PW - 1],  w21 = bp[PW],  w22 = bp[PW + 1];

    const float* xp = x + ((size_t)n * Cc + obase) * HWp + hw;
    OutT* op = out1 + ((size_t)n * Cc + obase) * HWp + hw;
    uint32_t m2 = 0;

    auto body = [&](auto base_of) {
        #pragma unroll 1
        for (int jc = 0; jc < 32; jc += 8) {
            float xv[8];
            #pragma unroll
            for (int j = 0; j < 8; ++j) xv[j] = xp[(size_t)(jc + j) * HWp];
            #pragma unroll
            for (int j = 0; j < 8; ++j) {
                int o = obase + jc + j;
                const uint64_t* wo = wb + o * 9;
                int s;
                s  = (int)__popcll(w00 ^ wo[0]);
                s += (int)__popcll(w01 ^ wo[1]);
                s += (int)__popcll(w02 ^ wo[2]);
                s += (int)__popcll(w10 ^ wo[3]);
                s += (int)__popcll(w11 ^ wo[4]);
                s += (int)__popcll(w12 ^ wo[5]);
                s += (int)__popcll(w20 ^ wo[6]);
                s += (int)__popcll(w21 ^ wo[7]);
                s += (int)__popcll(w22 ^ wo[8]);
                int m = base_of(o) - (s << 1);
                float v = fmaf(asc[o], (float)m, xv[j]);
                v += b12[o];
                v = v >= 0.f ? v : a1[o] * v;
                v += b13[o];
                op[(size_t)(jc + j) * HWp] = (OutT)v;
                if (v + b21[o] < 0.f) m2 |= (1u << (jc + j));
            }
        }
    };
    if (interior) body([&](int) { return 576; });
    else          body([&](int o) { return cint[o * 9 + t9]; });

    bits2_32[((size_t)n * PHW + (h + 1) * PW + (w + 1)) * 2 + z] = m2;
}

// conv2 + residual(out1) + b22/prelu(a2)/b23 -> out (fp32). Same structure.
template <typename InT>
__global__ __launch_bounds__(256) void conv2_ep(
        const uint64_t* __restrict__ bits2, const InT* __restrict__ out1,
        const uint64_t* __restrict__ wb, const float* __restrict__ asc,
        const int* __restrict__ cint,
        const float* __restrict__ b22, const float* __restrict__ a2,
        const float* __restrict__ b23, float* __restrict__ out) {
    int n = blockIdx.y, z = blockIdx.z, obase = z * 32;
    int bx = blockIdx.x;
    bool interior = (bx < NINT_BLK);
    int h, w, t9 = 4;
    if (interior) {
        int p = bx * 256 + threadIdx.x;
        if (p >= IPX) return;
        int ph = p / IW;
        h = 1 + ph; w = 1 + (p - ph * IW);
    } else {
        int p = (bx - NINT_BLK) * 256 + threadIdx.x;
        if (p >= BPX) return;
        border_map(p, h, w);
        t9 = ((h == 0) ? 0 : (h == Hh - 1) ? 6 : 3) +
             ((w == 0) ? 0 : (w == Ww - 1) ? 2 : 1);
    }
    int hw = h * Ww + w;
    const uint64_t* bp = bits2 + (size_t)n * PHW + (h + 1) * PW + (w + 1);
    uint64_t w00 = bp[-PW - 1], w01 = bp[-PW], w02 = bp[-PW + 1];
    uint64_t w10 = bp[-1],      w11 = bp[0],   w12 = bp[1];
    uint64_t w20 = bp[PW - 1],  w21 = bp[PW],  w22 = bp[PW + 1];

    const InT* ip = out1 + ((size_t)n * Cc + obase) * HWp + hw;
    float* op = out + ((size_t)n * Cc + obase) * HWp + hw;

    auto body = [&](auto base_of) {
        #pragma unroll 1
        for (int jc = 0; jc < 32; jc += 8) {
            InT rv[8];
            #pragma unroll
            for (int j = 0; j < 8; ++j) rv[j] = ip[(size_t)(jc + j) * HWp];
            #pragma unroll
            for (int j = 0; j < 8; ++j) {
                int o = obase + jc + j;
                const uint64_t* wo = wb + o * 9;
                int s;
                s  = (int)__popcll(w00 ^ wo[0]);
                s += (int)__popcll(w01 ^ wo[1]);
                s += (int)__popcll(w02 ^ wo[2]);
                s += (int)__popcll(w10 ^ wo[3]);
                s += (int)__popcll(w11 ^ wo[4]);
                s += (int)__popcll(w12 ^ wo[5]);
                s += (int)__popcll(w20 ^ wo[6]);
                s += (int)__popcll(w21 ^ wo[7]);
                s += (int)__popcll(w22 ^ wo[8]);
                int m = base_of(o) - (s << 1);
                float v = fmaf(asc[o], (float)m, (float)rv[j]);
                v += b22[o];
                v = v >= 0.f ? v : a2[o] * v;
                v += b23[o];
                op[(size_t)(jc + j) * HWp] = v;
            }
        }
    };
    if (interior) body([&](int) { return 576; });
    else          body([&](int o) { return cint[o * 9 + t9]; });
}

extern "C" void kernel_launch(void* const* d_in, const int* in_sizes, int n_in,
                              void* d_out, int out_size, void* d_ws, size_t ws_size,
                              hipStream_t stream) {
    const float* x    = (const float*)d_in[0];
    const float* w3   = (const float*)d_in[1];
    const float* wpw  = (const float*)d_in[2];
    const float* b11  = (const float*)d_in[3];
    const float* b12  = (const float*)d_in[4];
    const float* b13  = (const float*)d_in[5];
    const float* b21  = (const float*)d_in[6];
    const float* b22  = (const float*)d_in[7];
    const float* b23  = (const float*)d_in[8];
    const float* a1   = (const float*)d_in[9];
    const float* a2   = (const float*)d_in[10];

    char* ws = (char*)d_ws;
    uint64_t* wb1   = (uint64_t*)(ws + WB1_OFF);
    uint64_t* wb2   = (uint64_t*)(ws + WB2_OFF);
    float*    asc1  = (float*)(ws + ASC1_OFF);
    float*    asc2  = (float*)(ws + ASC2_OFF);
    int*      ci1   = (int*)(ws + CI1_OFF);
    int*      ci2   = (int*)(ws + CI2_OFF);
    uint64_t* bits1 = (uint64_t*)(ws + BITS1_OFF);
    uint64_t* bits2 = (uint64_t*)(ws + BITS2_OFF);
    float*    out   = (float*)d_out;

    dim3 pgrid((PHW + 255) / 256, Bn, 2);      // 51 x 32 x 2
    dim3 cgrid(NINT_BLK + 2, Bn, 2);           // 50 x 32 x 2

    prep_weights<<<128, 64, 0, stream>>>(w3, wpw, wb1, wb2, asc1, asc2, ci1, ci2);
    pack1<<<pgrid, 256, 0, stream>>>(x, b11, (uint32_t*)bits1, (uint32_t*)bits2);

    if (ws_size >= WS_NEED) {
        __half* out1h = (__half*)(ws + OUT1H_OFF);
        conv1_ep<__half><<<cgrid, 256, 0, stream>>>(x, bits1, wb1, asc1, ci1,
                                                    b12, a1, b13, b21, out1h,
                                                    (uint32_t*)bits2);
        conv2_ep<__half><<<cgrid, 256, 0, stream>>>(bits2, out1h, wb2, asc2, ci2,
                                                    b22, a2, b23, out);
    } else {
        conv1_ep<float><<<cgrid, 256, 0, stream>>>(x, bits1, wb1, asc1, ci1,
                                                   b12, a1, b13, b21, out,
                                                   (uint32_t*)bits2);
        conv2_ep<float><<<cgrid, 256, 0, stream>>>(bits2, out, wb2, asc2, ci2,
                                                   b22, a2, b23, out);
    }
}